// Round 1
// 462.500 us; speedup vs baseline: 1.0343x; 1.0343x over previous
//
#include <hip/hip_runtime.h>
#include <cstdint>

#define N_NODES 20000
#define N_EDGES 320000
#define ALPHA 0.2f
#define GAT_EPS 1e-16f
#define MPAD 20096           // 157 * 128
#define RBLK 157
#define RHI 20               // ceil(157/8)
#define SCAN_BLKS 80
#define BT_ROWS 1152         // 9 col-blocks * 128

typedef __attribute__((ext_vector_type(8))) _Float16 half8;
typedef __attribute__((ext_vector_type(4))) _Float16 half4t;
typedef __attribute__((ext_vector_type(16))) float f32x16;
typedef __attribute__((ext_vector_type(2))) float f32x2;

__device__ __forceinline__ float elu1(float x) { return x > 0.f ? x : __expf(x) - 1.f; }

__device__ __forceinline__ unsigned char f2fp8(float x) {
    return (unsigned char)(__builtin_amdgcn_cvt_pk_fp8_f32(x, 0.f, 0, false) & 0xff);
}

__device__ __forceinline__ void async16(const void* g, void* l) {
    __builtin_amdgcn_global_load_lds(
        (const __attribute__((address_space(1))) unsigned int*)g,
        (__attribute__((address_space(3))) unsigned int*)l, 16, 0, 0);
}

__device__ __forceinline__ float rdlanef(float v, int j) {
    return __int_as_float(__builtin_amdgcn_readlane(__float_as_int(v), j));
}

// ---------------- CSR build ----------------
__global__ void hist_kernel(const int* __restrict__ dst, int* __restrict__ counts, int E) {
    int e = blockIdx.x * blockDim.x + threadIdx.x;
    if (e < E) atomicAdd(&counts[dst[e]], 1);
}

__global__ void scan1_kernel(const int* __restrict__ counts, int* __restrict__ excl,
                             int* __restrict__ partial, int N) {
    __shared__ int sh[256];
    int t = threadIdx.x, b = blockIdx.x;
    int i = b * 256 + t;
    int v = (i < N) ? counts[i] : 0;
    sh[t] = v;
    __syncthreads();
    for (int d = 1; d < 256; d <<= 1) {
        int x = (t >= d) ? sh[t - d] : 0;
        __syncthreads();
        sh[t] += x;
        __syncthreads();
    }
    if (i < N) excl[i] = sh[t] - v;
    if (t == 255) partial[b] = sh[255];
}

__global__ void scan2_kernel(int* __restrict__ partial) {
    __shared__ int sh[128];
    int t = threadIdx.x;
    int v = (t < SCAN_BLKS) ? partial[t] : 0;
    sh[t] = v;
    __syncthreads();
    for (int d = 1; d < 128; d <<= 1) {
        int x = (t >= d) ? sh[t - d] : 0;
        __syncthreads();
        sh[t] += x;
        __syncthreads();
    }
    if (t < SCAN_BLKS) partial[t] = sh[t] - v;
}

__global__ void scan3_kernel(const int* __restrict__ excl, const int* __restrict__ partial,
                             int* __restrict__ rowptr, int* __restrict__ cursor, int N, int E) {
    int t = threadIdx.x, b = blockIdx.x;
    int i = b * 256 + t;
    if (i < N) {
        int v = excl[i] + partial[b];
        rowptr[i] = v;
        cursor[i] = v;
    }
    if (i == 0) rowptr[N] = E;
}

__global__ void scatter_kernel(const int* __restrict__ src, const int* __restrict__ dst,
                               int* __restrict__ cursor, int* __restrict__ esrc, int E) {
    int e = blockIdx.x * blockDim.x + threadIdx.x;
    if (e < E) {
        int p = atomicAdd(&cursor[dst[e]], 1);
        esrc[p] = src[e];
    }
}

// ---------------- packs ----------------
__global__ void pack_x16(const float* __restrict__ x, _Float16* __restrict__ A) {
    int idx = blockIdx.x * 256 + threadIdx.x;   // MPAD*64
    int r = idx >> 6, c = idx & 63;
    float v = (r < N_NODES && c < 50) ? x[r * 50 + c] : 0.f;
    A[idx] = (_Float16)v;
}

__global__ void pack_bt1(const float* __restrict__ W, _Float16* __restrict__ Bt) {
    int idx = blockIdx.x * 256 + threadIdx.x;   // 1024*64
    int c = idx >> 6, k = idx & 63;
    int h = c >> 8, f = c & 255;
    float v = (k < 50) ? W[((size_t)h * 50 + k) * 256 + f] : 0.f;
    Bt[idx] = (_Float16)v;
}

// generic: BT row c -> head h=c/Fpad, col f=c%Fpad; zero for f>=F (alignment pad)
__global__ void pack_bt16(const float* __restrict__ W, _Float16* __restrict__ Bt,
                          int F, int Fpad, int Ctot) {
    int c = blockIdx.y;
    int k = blockIdx.x * blockDim.x + threadIdx.x;
    float v = 0.f;
    if (c < Ctot) {
        int h = c / Fpad, f = c - h * Fpad;
        if (f < F) v = W[(size_t)h * 1024 * F + (size_t)k * F + f];
    }
    Bt[(size_t)c * 1024 + k] = (_Float16)v;
}

// W~ cols appended at BT rows [Nfeat, Nfeat+2H); gridDim.y MUST be 2*H.
__global__ __launch_bounds__(64) void wtilde_kernel(const float* __restrict__ W,
                                                    const float* __restrict__ a,
                                                    _Float16* __restrict__ BT, int Kreal,
                                                    int Kdim, int F, int H, int Nfeat) {
    int k = blockIdx.x, j = blockIdx.y;
    if (j >= 2 * H) return;
    int lane = threadIdx.x;
    int h = j < H ? j : j - H;
    int ao = j < H ? 0 : F;
    float s = 0.f;
    if (k < Kreal) {
        const float* wp = W + ((size_t)h * Kreal + k) * F;
        const float* ap = a + (size_t)h * 2 * F + ao;
        for (int f = lane; f < F; f += 64) s += wp[f] * ap[f];
    }
#pragma unroll
    for (int off = 32; off; off >>= 1) s += __shfl_down(s, off);
    if (lane == 0) BT[(size_t)(Nfeat + j) * Kdim + k] = (_Float16)s;
}

// ---------------- fp16 MFMA GEMM (32x32x16) -> fp8 Wh + fp32 score cols ----------------
// Double-buffered LDS + next-tile prefetch issued BEFORE the MFMA cluster
// ("minimum 2-phase" pipeline): loads of tile t+1 are in flight while tile t computes;
// one vmcnt-drain+barrier per K-step instead of a dead drain between stage and compute.
__global__ __launch_bounds__(256) void gemm_f16(const _Float16* __restrict__ A,
                                                const _Float16* __restrict__ BT,
                                                unsigned char* __restrict__ C8,
                                                float* __restrict__ SPRE,
                                                int M, int Nfeat, int ld, int Kdim, int Cblk) {
    int id = blockIdx.x;
    int xm = id & 7, q = id >> 3;
    int cb = q % Cblk, rh = q / Cblk;
    int rb = rh * 8 + xm;
    if (rb >= RBLK) return;
    __shared__ __align__(16) _Float16 sA[2][128 * 64];
    __shared__ __align__(16) _Float16 sB[2][128 * 64];
    int t = threadIdx.x;
    int row0 = rb * 128, col0 = cb * 128;
    int lane = t & 63, wave = t >> 6;
    int wm = wave >> 1, wn = wave & 1;
    int l31 = lane & 31;
    int lhi = lane >> 5;

    const _Float16* gA = A + (size_t)row0 * Kdim;
    const _Float16* gB = BT + (size_t)col0 * Kdim;

    int sR[4], sgl[4];
#pragma unroll
    for (int i = 0; i < 4; i++) {
        int m = i * 256 + t;
        sR[i] = m >> 3;
        sgl[i] = (m & 7) ^ (sR[i] & 7);
    }

    f32x16 acc[2][2] = {};

    // prologue: stage K-tile 0 into buffer 0
#pragma unroll
    for (int i = 0; i < 4; i++) {
        const _Float16* pa = gA + (size_t)sR[i] * Kdim + sgl[i] * 8;
        const _Float16* pb = gB + (size_t)sR[i] * Kdim + sgl[i] * 8;
        async16(pa, &sA[0][(i * 256 + t) * 8]);
        async16(pb, &sB[0][(i * 256 + t) * 8]);
    }

    int cur = 0;
    for (int k0 = 0; k0 < Kdim; k0 += 64) {
        __syncthreads();           // drains vmcnt: buf[cur] staged; prev buf's ds_reads done
        int nxt = k0 + 64;
        if (nxt < Kdim) {
            int nb = cur ^ 1;      // issue next tile's loads BEFORE compute
#pragma unroll
            for (int i = 0; i < 4; i++) {
                const _Float16* pa = gA + (size_t)sR[i] * Kdim + nxt + sgl[i] * 8;
                const _Float16* pb = gB + (size_t)sR[i] * Kdim + nxt + sgl[i] * 8;
                async16(pa, &sA[nb][(i * 256 + t) * 8]);
                async16(pb, &sB[nb][(i * 256 + t) * 8]);
            }
        }
        const _Float16* cA = sA[cur];
        const _Float16* cB = sB[cur];
#pragma unroll
        for (int kk = 0; kk < 4; kk++) {
            int g = kk * 2 + lhi;
            half8 af[2], bf[2];
#pragma unroll
            for (int mt = 0; mt < 2; mt++) {
                int R = wm * 64 + mt * 32 + l31;
                int gp = g ^ (R & 7);
                af[mt] = *(const half8*)(cA + R * 64 + gp * 8);
            }
#pragma unroll
            for (int nt = 0; nt < 2; nt++) {
                int R = wn * 64 + nt * 32 + l31;
                int gp = g ^ (R & 7);
                bf[nt] = *(const half8*)(cB + R * 64 + gp * 8);
            }
#pragma unroll
            for (int mt = 0; mt < 2; mt++)
#pragma unroll
                for (int nt = 0; nt < 2; nt++)
                    acc[mt][nt] = __builtin_amdgcn_mfma_f32_32x32x16_f16(af[mt], bf[nt], acc[mt][nt], 0, 0, 0);
        }
        cur ^= 1;
    }

    int cb32 = col0 + wn * 64 + l31;
    int rb32 = row0 + wm * 64 + 4 * lhi;
#pragma unroll
    for (int mt = 0; mt < 2; mt++)
#pragma unroll
        for (int nt = 0; nt < 2; nt++) {
            int gc = cb32 + nt * 32;
            if (gc < Nfeat) {
#pragma unroll
                for (int r = 0; r < 16; r++) {
                    int gr = rb32 + mt * 32 + (r & 3) + 8 * (r >> 2);
                    if (gr < M) C8[(size_t)gr * ld + gc] = f2fp8(acc[mt][nt][r]);
                }
            } else if (gc < Nfeat + 12) {
                int j = gc - Nfeat;
#pragma unroll
                for (int r = 0; r < 16; r++) {
                    int gr = rb32 + mt * 32 + (r & 3) + 8 * (r >> 2);
                    if (gr < M) SPRE[(size_t)j * N_NODES + gr] = acc[mt][nt][r];
                }
            }
        }
}

// ---------------- fused attention + aggregation, Fout=256 layers ----------------
// one block per node, wave = head. Phase 1: online softmax stats (lanes over edges).
// Phase 2: per-edge broadcast of (p, src) via v_readlane, lanes over features
// (dword fp8 gather = 256 B per wave, all 4 head-waves cover the same 1 KiB row
// concurrently -> L2-local). Kills the E*H ATT round-trip and 3 extra dispatches.
__global__ __launch_bounds__(256) void attagg256_kernel(const int* __restrict__ rowptr,
                                                        const int* __restrict__ esrc,
                                                        const float* __restrict__ SPRE,
                                                        const unsigned char* __restrict__ WH8,
                                                        _Float16* __restrict__ X16,
                                                        int use_skip, int N) {
    int n = blockIdx.x;
    int h = threadIdx.x >> 6;
    int lane = threadIdx.x & 63;
    int start = rowptr[n], end = rowptr[n + 1];
    const float* ss = SPRE + (size_t)h * N;
    float sd = SPRE[(size_t)(4 + h) * N + n];

    // ---- phase 1: online softmax (m, s) ----
    float m = -1e30f, s = 0.f;
    int sidx = 0; float ssc = -1e30f;   // last chunk's per-lane score (reused in phase 2)
    for (int e0 = start; e0 < end; e0 += 64) {
        int e = e0 + lane;
        bool act = e < end;
        int idx = act ? esrc[e] : 0;
        float sc = -1e30f;
        if (act) {
            sc = ss[idx] + sd;
            sc = sc > 0.f ? sc : ALPHA * sc;
        }
        sidx = idx; ssc = sc;
        float mn = fmaxf(m, sc);
        s = s * __expf(m - mn) + (act ? __expf(sc - mn) : 0.f);
        m = mn;
    }
#pragma unroll
    for (int off = 1; off < 64; off <<= 1) {
        float mo = __shfl_xor(m, off);
        float so = __shfl_xor(s, off);
        float mn = fmaxf(m, mo);
        s = s * __expf(m - mn) + so * __expf(mo - mn);
        m = mn;
    }
    float inv = 1.f / (s + GAT_EPS);

    // ---- phase 2: weighted aggregation ----
    const unsigned char* Wb = WH8 + h * 256 + lane * 4;
    float a0 = 0.f, a1 = 0.f, a2 = 0.f, a3 = 0.f;
    int lastStart = start + (((end - start - 1) >> 6) << 6);   // valid when end>start
    for (int e0 = start; e0 < end; e0 += 64) {
        int e = e0 + lane;
        bool act = e < end;
        int idx; float sc;
        if (e0 == lastStart) { idx = sidx; sc = ssc; }
        else {
            idx = act ? esrc[e] : 0;
            sc = -1e30f;
            if (act) {
                sc = ss[idx] + sd;
                sc = sc > 0.f ? sc : ALPHA * sc;
            }
        }
        float p = act ? __expf(sc - m) * inv : 0.f;
        int cnt = end - e0; if (cnt > 64) cnt = 64;
        int j = 0;
        for (; j + 4 <= cnt; j += 4) {
            int i0 = __builtin_amdgcn_readlane(idx, j);
            int i1 = __builtin_amdgcn_readlane(idx, j + 1);
            int i2 = __builtin_amdgcn_readlane(idx, j + 2);
            int i3 = __builtin_amdgcn_readlane(idx, j + 3);
            float p0 = rdlanef(p, j), p1 = rdlanef(p, j + 1);
            float p2 = rdlanef(p, j + 2), p3 = rdlanef(p, j + 3);
            unsigned int w0 = *(const unsigned int*)(Wb + (size_t)i0 * 1024);
            unsigned int w1 = *(const unsigned int*)(Wb + (size_t)i1 * 1024);
            unsigned int w2 = *(const unsigned int*)(Wb + (size_t)i2 * 1024);
            unsigned int w3 = *(const unsigned int*)(Wb + (size_t)i3 * 1024);
            f32x2 l0 = __builtin_amdgcn_cvt_pk_f32_fp8((int)w0, false);
            f32x2 h0v = __builtin_amdgcn_cvt_pk_f32_fp8((int)w0, true);
            f32x2 l1 = __builtin_amdgcn_cvt_pk_f32_fp8((int)w1, false);
            f32x2 h1v = __builtin_amdgcn_cvt_pk_f32_fp8((int)w1, true);
            f32x2 l2 = __builtin_amdgcn_cvt_pk_f32_fp8((int)w2, false);
            f32x2 h2v = __builtin_amdgcn_cvt_pk_f32_fp8((int)w2, true);
            f32x2 l3 = __builtin_amdgcn_cvt_pk_f32_fp8((int)w3, false);
            f32x2 h3v = __builtin_amdgcn_cvt_pk_f32_fp8((int)w3, true);
            a0 += p0 * l0.x + p1 * l1.x + p2 * l2.x + p3 * l3.x;
            a1 += p0 * l0.y + p1 * l1.y + p2 * l2.y + p3 * l3.y;
            a2 += p0 * h0v.x + p1 * h1v.x + p2 * h2v.x + p3 * h3v.x;
            a3 += p0 * h0v.y + p1 * h1v.y + p2 * h2v.y + p3 * h3v.y;
        }
        for (; j < cnt; j++) {
            int ij = __builtin_amdgcn_readlane(idx, j);
            float pj = rdlanef(p, j);
            unsigned int w = *(const unsigned int*)(Wb + (size_t)ij * 1024);
            f32x2 lo = __builtin_amdgcn_cvt_pk_f32_fp8((int)w, false);
            f32x2 hi = __builtin_amdgcn_cvt_pk_f32_fp8((int)w, true);
            a0 += pj * lo.x; a1 += pj * lo.y; a2 += pj * hi.x; a3 += pj * hi.y;
        }
    }

    size_t o = (size_t)n * 1024 + h * 256 + lane * 4;
    float v0, v1, v2, v3;
    if (use_skip) {
        half4t sk = *(const half4t*)(X16 + o);
        v0 = elu1(elu1(a0) + (float)sk.x);
        v1 = elu1(elu1(a1) + (float)sk.y);
        v2 = elu1(elu1(a2) + (float)sk.z);
        v3 = elu1(elu1(a3) + (float)sk.w);
    } else {
        v0 = elu1(elu1(a0)); v1 = elu1(elu1(a1));
        v2 = elu1(elu1(a2)); v3 = elu1(elu1(a3));
    }
    half4t r;
    r.x = (_Float16)v0; r.y = (_Float16)v1; r.z = (_Float16)v2; r.w = (_Float16)v3;
    *(half4t*)(X16 + o) = r;
}

// ---------------- fused attention + aggregation, layer 3 (6 heads, Fout=121) ----------
// block = node, 6 waves = 6 heads. Phase 1 as above; phase 2: lanes 0..61 gather uchar2
// at h*124 + 2*lane of each source row (pad cols 121..123 are exact GEMM zeros);
// lanes 62/63 gather harmlessly and are discarded at the LDS write.
__global__ __launch_bounds__(384) void attagg726_kernel(const int* __restrict__ rowptr,
                                                        const int* __restrict__ esrc,
                                                        const float* __restrict__ SPRE,
                                                        const unsigned char* __restrict__ WH8,
                                                        float* __restrict__ out, int N) {
    __shared__ float part[6][124];
    int n = blockIdx.x;
    int t = threadIdx.x;
    int h = t >> 6;
    int lane = t & 63;
    int start = rowptr[n], end = rowptr[n + 1];
    const float* ss = SPRE + (size_t)h * N;
    float sd = SPRE[(size_t)(6 + h) * N + n];

    float m = -1e30f, s = 0.f;
    int sidx = 0; float ssc = -1e30f;
    for (int e0 = start; e0 < end; e0 += 64) {
        int e = e0 + lane;
        bool act = e < end;
        int idx = act ? esrc[e] : 0;
        float sc = -1e30f;
        if (act) {
            sc = ss[idx] + sd;
            sc = sc > 0.f ? sc : ALPHA * sc;
        }
        sidx = idx; ssc = sc;
        float mn = fmaxf(m, sc);
        s = s * __expf(m - mn) + (act ? __expf(sc - mn) : 0.f);
        m = mn;
    }
#pragma unroll
    for (int off = 1; off < 64; off <<= 1) {
        float mo = __shfl_xor(m, off);
        float so = __shfl_xor(s, off);
        float mn = fmaxf(m, mo);
        s = s * __expf(m - mn) + so * __expf(mo - mn);
        m = mn;
    }
    float inv = 1.f / (s + GAT_EPS);

    const unsigned char* Wb = WH8 + h * 124 + 2 * lane;
    float a0 = 0.f, a1 = 0.f;
    int lastStart = start + (((end - start - 1) >> 6) << 6);
    for (int e0 = start; e0 < end; e0 += 64) {
        int e = e0 + lane;
        bool act = e < end;
        int idx; float sc;
        if (e0 == lastStart) { idx = sidx; sc = ssc; }
        else {
            idx = act ? esrc[e] : 0;
            sc = -1e30f;
            if (act) {
                sc = ss[idx] + sd;
                sc = sc > 0.f ? sc : ALPHA * sc;
            }
        }
        float p = act ? __expf(sc - m) * inv : 0.f;
        int cnt = end - e0; if (cnt > 64) cnt = 64;
        int j = 0;
        for (; j + 4 <= cnt; j += 4) {
            int i0 = __builtin_amdgcn_readlane(idx, j);
            int i1 = __builtin_amdgcn_readlane(idx, j + 1);
            int i2 = __builtin_amdgcn_readlane(idx, j + 2);
            int i3 = __builtin_amdgcn_readlane(idx, j + 3);
            float p0 = rdlanef(p, j), p1 = rdlanef(p, j + 1);
            float p2 = rdlanef(p, j + 2), p3 = rdlanef(p, j + 3);
            unsigned short w0 = *(const unsigned short*)(Wb + (size_t)i0 * 768);
            unsigned short w1 = *(const unsigned short*)(Wb + (size_t)i1 * 768);
            unsigned short w2 = *(const unsigned short*)(Wb + (size_t)i2 * 768);
            unsigned short w3 = *(const unsigned short*)(Wb + (size_t)i3 * 768);
            f32x2 f0 = __builtin_amdgcn_cvt_pk_f32_fp8((int)w0, false);
            f32x2 f1 = __builtin_amdgcn_cvt_pk_f32_fp8((int)w1, false);
            f32x2 f2 = __builtin_amdgcn_cvt_pk_f32_fp8((int)w2, false);
            f32x2 f3 = __builtin_amdgcn_cvt_pk_f32_fp8((int)w3, false);
            a0 += p0 * f0.x + p1 * f1.x + p2 * f2.x + p3 * f3.x;
            a1 += p0 * f0.y + p1 * f1.y + p2 * f2.y + p3 * f3.y;
        }
        for (; j < cnt; j++) {
            int ij = __builtin_amdgcn_readlane(idx, j);
            float pj = rdlanef(p, j);
            unsigned short w = *(const unsigned short*)(Wb + (size_t)ij * 768);
            f32x2 f = __builtin_amdgcn_cvt_pk_f32_fp8((int)w, false);
            a0 += pj * f.x; a1 += pj * f.y;
        }
    }
    if (lane < 62) {
        part[h][2 * lane]     = a0;
        part[h][2 * lane + 1] = a1;
    }
    __syncthreads();
    if (t < 121) {
        float tot = (part[0][t] + part[1][t] + part[2][t] +
                     part[3][t] + part[4][t] + part[5][t]) * (1.f / 6.f);
        out[(size_t)n * 121 + t] = 1.f / (1.f + __expf(-tot));
    }
}

extern "C" void kernel_launch(void* const* d_in, const int* in_sizes, int n_in,
                              void* d_out, int out_size, void* d_ws, size_t ws_size,
                              hipStream_t stream) {
    const float* x  = (const float*)d_in[0];
    const int*   ei = (const int*)d_in[1];
    const float* W1 = (const float*)d_in[2];
    const float* a1 = (const float*)d_in[3];
    const float* W2 = (const float*)d_in[4];
    const float* a2 = (const float*)d_in[5];
    const float* W3 = (const float*)d_in[6];
    const float* a3 = (const float*)d_in[7];
    float* out = (float*)d_out;
    const int N = N_NODES, E = N_EDGES;
    const int* src = ei;
    const int* dst = ei + E;

    char* ws = (char*)d_ws;
    size_t off = 0;
    auto alloc = [&](size_t b) { size_t o = off; off += (b + 255) & ~(size_t)255; return o; };
    _Float16* X16  = (_Float16*)(ws + alloc((size_t)MPAD * 1024 * 2));  // x1 then x2 (fp16)
    unsigned char* WH8 = (unsigned char*)(ws + alloc((size_t)MPAD * 1024)); // per-layer Wh (fp8)
    _Float16* BT16 = (_Float16*)(ws + alloc((size_t)BT_ROWS * 1024 * 2));
    _Float16* A1   = (_Float16*)(ws + alloc((size_t)MPAD * 64 * 2));
    _Float16* BT1  = (_Float16*)(ws + alloc((size_t)BT_ROWS * 64 * 2));
    float* SPRE   = (float*)(ws + alloc((size_t)12 * N * 4));
    int*   rowptr = (int*)(ws + alloc((size_t)(N + 1) * 4));
    int*   cursor = (int*)(ws + alloc((size_t)N * 4));
    int*   counts = (int*)(ws + alloc((size_t)N * 4));
    int*   excl   = (int*)(ws + alloc((size_t)N * 4));
    int*   partial= (int*)(ws + alloc((size_t)SCAN_BLKS * 4));
    int*   esrc   = (int*)(ws + alloc((size_t)E * 4));

    // CSR by dst
    hipMemsetAsync(counts, 0, (size_t)N * 4, stream);
    hist_kernel<<<(E + 255) / 256, 256, 0, stream>>>(dst, counts, E);
    scan1_kernel<<<SCAN_BLKS, 256, 0, stream>>>(counts, excl, partial, N);
    scan2_kernel<<<1, 128, 0, stream>>>(partial);
    scan3_kernel<<<SCAN_BLKS, 256, 0, stream>>>(excl, partial, rowptr, cursor, N, E);
    scatter_kernel<<<(E + 255) / 256, 256, 0, stream>>>(src, dst, cursor, esrc, E);
    hipMemsetAsync(X16 + (size_t)N * 1024, 0, (size_t)(MPAD - N) * 1024 * 2, stream);

    // ---- layer 1: 50 -> 4x256 concat ----
    pack_x16<<<MPAD * 64 / 256, 256, 0, stream>>>(x, A1);
    pack_bt1<<<1024 * 64 / 256, 256, 0, stream>>>(W1, BT1);
    wtilde_kernel<<<dim3(64, 8), 64, 0, stream>>>(W1, a1, BT1, 50, 64, 256, 4, 1024);
    gemm_f16<<<8 * RHI * 9, 256, 0, stream>>>(A1, BT1, WH8, SPRE, N, 1024, 1024, 64, 9);
    attagg256_kernel<<<N, 256, 0, stream>>>(rowptr, esrc, SPRE, WH8, X16, 0, N);

    // ---- layer 2: 1024 -> 4x256 concat + skip ----
    pack_bt16<<<dim3(4, 1024), 256, 0, stream>>>(W2, BT16, 256, 256, 1024);
    wtilde_kernel<<<dim3(1024, 8), 64, 0, stream>>>(W2, a2, BT16, 1024, 1024, 256, 4, 1024);
    gemm_f16<<<8 * RHI * 9, 256, 0, stream>>>(X16, BT16, WH8, SPRE, N, 1024, 1024, 1024, 9);
    attagg256_kernel<<<N, 256, 0, stream>>>(rowptr, esrc, SPRE, WH8, X16, 1, N);

    // ---- layer 3: 1024 -> 6x121 (stride 124, zero-padded), mean + sigmoid ----
    pack_bt16<<<dim3(4, 744), 256, 0, stream>>>(W3, BT16, 121, 124, 744);
    wtilde_kernel<<<dim3(1024, 12), 64, 0, stream>>>(W3, a3, BT16, 1024, 1024, 121, 6, 744);
    gemm_f16<<<8 * RHI * 6, 256, 0, stream>>>(X16, BT16, WH8, SPRE, N, 744, 768, 1024, 6);
    attagg726_kernel<<<N, 384, 0, stream>>>(rowptr, esrc, SPRE, WH8, out, N);
}